// Round 6
// baseline (205.225 us; speedup 1.0000x reference)
//
#include <hip/hip_runtime.h>
#include <math.h>

#define HH 96
#define WW 96
#define CC 64
#define NH 4
#define HD 16
#define KS 13
#define KK (KS*KS)
#define NTOK (HH*WW)

// ---------------- DPP cross-lane add (pure VALU, no LDS pipe) ---------------
// ctrl 0xB1 = quad_perm(1,0,3,2)  -> xor1 within quad
// ctrl 0x4E = quad_perm(2,3,0,1)  -> xor2 within quad
// ctrl 0x141 = row_half_mirror (valid only when quads already uniform)
template<int CTRL>
__device__ __forceinline__ float dpp_add(float p) {
    int t = __builtin_amdgcn_update_dpp(0, __float_as_int(p), CTRL, 0xF, 0xF, true);
    return p + __int_as_float(t);
}

__device__ __forceinline__ float dpp_reduce8(float p) {
    p = dpp_add<0xB1>(p);
    p = dpp_add<0x4E>(p);
    p = dpp_add<0x141>(p);
    return p;
}

// In-place LayerNorm of a 32-token tile stored TRANSPOSED in LDS: buf[ch][tok],
// ch = 0..63, tok = 0..31. 256 threads: 8 lanes per row, 8 channels per lane.
__device__ __forceinline__ void ln_rows32(float (*buf)[34],
                                          const float* __restrict__ g,
                                          const float* __restrict__ b,
                                          int tid) {
    int r  = tid >> 3;
    int c0 = (tid & 7) * 8;
    float v[8];
    float s = 0.0f;
    #pragma unroll
    for (int j = 0; j < 8; j++) { v[j] = buf[c0 + j][r]; s += v[j]; }
    s = dpp_reduce8(s);
    float mu = s * (1.0f / 64.0f);
    float s2 = 0.0f;
    #pragma unroll
    for (int j = 0; j < 8; j++) { float d = v[j] - mu; s2 += d * d; }
    s2 = dpp_reduce8(s2);
    float inv = rsqrtf(s2 * (1.0f / 64.0f) + 1e-5f);
    #pragma unroll
    for (int j = 0; j < 8; j++)
        buf[c0 + j][r] = (v[j] - mu) * inv * g[c0 + j] + b[c0 + j];
}

// ---------------- Fused LN1 + qkv GEMM --------------------------------------
__global__ __launch_bounds__(256) void ln_gemm_kernel(const float* __restrict__ x,
                                                      const float* __restrict__ g,
                                                      const float* __restrict__ b,
                                                      const float* __restrict__ W,
                                                      const float* __restrict__ bias,
                                                      float* __restrict__ out) {
    __shared__ float Ast[64][34];
    const int t0 = blockIdx.x * 32;
    const int tid = threadIdx.x;

    for (int i = tid; i < 32 * 64; i += 256) {
        int r = i >> 6, cc = i & 63;
        Ast[cc][r] = x[t0 * 64 + i];
    }
    __syncthreads();
    ln_rows32(Ast, g, b, tid);
    __syncthreads();

    const int tc = tid & 15;
    const int tr = tid >> 4;
    const int r0 = tr * 2;
    const int c  = blockIdx.y * 64 + tc * 4;

    float4 b4 = *(const float4*)&bias[c];
    float4 acc0 = b4, acc1 = b4;
    #pragma unroll 8
    for (int k = 0; k < 64; k++) {
        float2 a = *(const float2*)&Ast[k][r0];
        float4 w = *(const float4*)&W[k * 192 + c];
        acc0.x += a.x * w.x; acc0.y += a.x * w.y; acc0.z += a.x * w.z; acc0.w += a.x * w.w;
        acc1.x += a.y * w.x; acc1.y += a.y * w.y; acc1.z += a.y * w.z; acc1.w += a.y * w.w;
    }
    if (blockIdx.y == 0) {  // q section scaled by hd^-0.5 = 0.25
        acc0.x *= 0.25f; acc0.y *= 0.25f; acc0.z *= 0.25f; acc0.w *= 0.25f;
        acc1.x *= 0.25f; acc1.y *= 0.25f; acc1.z *= 0.25f; acc1.w *= 0.25f;
    }
    *(float4*)&out[(t0 + r0) * 192 + c] = acc0;
    *(float4*)&out[(t0 + r0 + 1) * 192 + c] = acc1;
}

// ---------------- Neighborhood attention: one wave per FOUR tokens ----------
// qkv per token: [q(0..63) | k(64..127) | v(128..191)], head-major (n*16+d).
// Tokens (y, g, iw0..iw0+3): same row window (sh/rh shared); column windows
// overlap 12/13, union provably within [cbase, cbase+15], cbase=clamp(iw0-6).
// Lane = head(2b) | u(2b) | l(2b): u = token index, l = dim-quad (float4).
// Every k4/v4 load is consumed by all 4 tokens (4x L1-traffic reduction vs
// one-token-per-wave). Out-of-window (token,col) pairs masked via bias=-1e30
// -> exp = 0 exactly. No epilogue cross-lane reduction: each u-group owns its
// token; dot needs only 2 quad_perm DPP adds (quads = l-groups).
// Loads clamped in-bounds: col min(c,31) (always masked when c>31 since
// c-sw >= 13), bias idx min(rel,24) (rel >= 0 provable for all cases).
__global__ __launch_bounds__(256) void na_attn_kernel(const float* __restrict__ qkv,
                                                      const float* __restrict__ rpb,
                                                      float* __restrict__ out) {
    int wave = threadIdx.x >> 6;
    int lane = threadIdx.x & 63;
    int wid  = blockIdx.x * 4 + wave;        // 0..2303
    int y    = wid / 24;                     // spatial row
    int rem  = wid - y * 24;
    int g    = rem >> 3;                     // column group (x % 3)
    int iw0  = (rem & 7) * 4;                // first token's group-col

    int head = lane >> 4;
    int u    = (lane >> 2) & 3;              // token index within wave
    int l    = lane & 3;                     // dim-quad
    int co   = head * HD + l * 4;

    int iwu   = iw0 + u;
    int token = y * WW + g + 3 * iwu;

    int gh = y % 3, ih = y / 3;
    int sh = ih - 6; sh = sh < 0 ? 0 : (sh > 19 ? 19 : sh);
    int swu = iwu - 6; swu = swu < 0 ? 0 : (swu > 19 ? 19 : swu);
    int cbase = iw0 - 6; cbase = cbase < 0 ? 0 : (cbase > 19 ? 19 : cbase);

    float4 q4 = *(const float4*)&qkv[token * 192 + co];
    const float* bias_h = rpb + head * 625;

    float4 acc = make_float4(0.f, 0.f, 0.f, 0.f);
    float s = 0.0f;

    for (int kh = 0; kh < KS; kh++) {
        int ny = gh + 3 * (sh + kh);
        int rh = sh + kh - ih + 12;
        const float* rowp = qkv + (ny * WW + g) * 192 + 64 + co;
        const float* brow = bias_h + rh * 25;
        #pragma unroll
        for (int j = 0; j < 16; j++) {
            int c  = cbase + j;
            int cl = c > 31 ? 31 : c;                    // in-bounds load col
            float4 k4 = *(const float4*)(rowp + cl * 576);
            float4 v4 = *(const float4*)(rowp + cl * 576 + 64);
            int rel = c - iwu + 12;                      // >= 0 always
            float bias = brow[rel > 24 ? 24 : rel];
            unsigned kw = (unsigned)(c - swu);
            bias = (kw <= 12u) ? bias : -1e30f;          // mask -> exp = 0
            float p = q4.x * k4.x + q4.y * k4.y + q4.z * k4.z + q4.w * k4.w;
            p = dpp_add<0xB1>(p);
            p = dpp_add<0x4E>(p);                        // full 16-dim dot
            float e = __expf(p + bias);
            s += e;
            acc.x += e * v4.x; acc.y += e * v4.y; acc.z += e * v4.z; acc.w += e * v4.w;
        }
    }

    float inv = 1.0f / s;
    *(float4*)&out[token * CC + co] =
        make_float4(acc.x * inv, acc.y * inv, acc.z * inv, acc.w * inv);
}

// ---------------- Fused proj+resid -> LN2 -> fc1+gelu -> fc2+resid ----------
__global__ __launch_bounds__(256) void mlp_fused_kernel(const float* __restrict__ attn_out,
                                                        const float* __restrict__ x,
                                                        const float* __restrict__ proj_w,
                                                        const float* __restrict__ proj_b,
                                                        const float* __restrict__ n2g,
                                                        const float* __restrict__ n2b,
                                                        const float* __restrict__ fc1_w,
                                                        const float* __restrict__ fc1_b,
                                                        const float* __restrict__ fc2_w,
                                                        const float* __restrict__ fc2_b,
                                                        float* __restrict__ out) {
    __shared__ float Ast[64][34];    // attn_out^T tile
    __shared__ float X2T[64][34];    // x2^T, then h2^T after LN
    __shared__ float Hid[256][34];   // hidden^T (gelu(fc1)) for fc2

    const int t0 = blockIdx.x * 32;
    const int tid = threadIdx.x;

    for (int i = tid; i < 32 * 64; i += 256) {
        int r = i >> 6, cc = i & 63;
        Ast[cc][r] = attn_out[t0 * 64 + i];
    }
    __syncthreads();

    const int tc = tid & 15;
    const int tr = tid >> 4;
    const int r0 = tr * 2;
    const int c  = tc * 4;

    // ---- proj + residual(x): x2 kept in registers (a0,a1) ----
    float4 pb = *(const float4*)&proj_b[c];
    float4 a0 = pb, a1 = pb;
    #pragma unroll 8
    for (int k = 0; k < 64; k++) {
        float2 a = *(const float2*)&Ast[k][r0];
        float4 w = *(const float4*)&proj_w[k * 64 + c];
        a0.x += a.x * w.x; a0.y += a.x * w.y; a0.z += a.x * w.z; a0.w += a.x * w.w;
        a1.x += a.y * w.x; a1.y += a.y * w.y; a1.z += a.y * w.z; a1.w += a.y * w.w;
    }
    {
        float4 x0 = *(const float4*)&x[(t0 + r0) * 64 + c];
        float4 x1 = *(const float4*)&x[(t0 + r0 + 1) * 64 + c];
        a0.x += x0.x; a0.y += x0.y; a0.z += x0.z; a0.w += x0.w;
        a1.x += x1.x; a1.y += x1.y; a1.z += x1.z; a1.w += x1.w;
    }
    X2T[c + 0][r0] = a0.x; X2T[c + 1][r0] = a0.y; X2T[c + 2][r0] = a0.z; X2T[c + 3][r0] = a0.w;
    X2T[c + 0][r0 + 1] = a1.x; X2T[c + 1][r0 + 1] = a1.y; X2T[c + 2][r0 + 1] = a1.z; X2T[c + 3][r0 + 1] = a1.w;
    __syncthreads();

    // ---- LN2 in place on X2T (raw x2 stays in a0/a1 for the final resid) ----
    ln_rows32(X2T, n2g, n2b, tid);
    __syncthreads();

    // ---- fc1 + gelu -> Hid (hidden^T). Each thread: 2 rows x 16 cols. ----
    float4 h0[4], h1[4];
    #pragma unroll
    for (int gg = 0; gg < 4; gg++) {
        float4 bb = *(const float4*)&fc1_b[c + gg * 64];
        h0[gg] = bb; h1[gg] = bb;
    }
    #pragma unroll 4
    for (int k = 0; k < 64; k++) {
        float2 a = *(const float2*)&X2T[k][r0];
        #pragma unroll
        for (int gg = 0; gg < 4; gg++) {
            float4 w = *(const float4*)&fc1_w[k * 256 + c + gg * 64];
            h0[gg].x += a.x * w.x; h0[gg].y += a.x * w.y; h0[gg].z += a.x * w.z; h0[gg].w += a.x * w.w;
            h1[gg].x += a.y * w.x; h1[gg].y += a.y * w.y; h1[gg].z += a.y * w.z; h1[gg].w += a.y * w.w;
        }
    }
    #define GELU1(v) v = 0.5f * v * (1.0f + erff(v * 0.70710678118f))
    #pragma unroll
    for (int gg = 0; gg < 4; gg++) {
        GELU1(h0[gg].x); GELU1(h0[gg].y); GELU1(h0[gg].z); GELU1(h0[gg].w);
        GELU1(h1[gg].x); GELU1(h1[gg].y); GELU1(h1[gg].z); GELU1(h1[gg].w);
    }
    #undef GELU1
    #pragma unroll
    for (int gg = 0; gg < 4; gg++) {
        int col = c + gg * 64;
        Hid[col + 0][r0] = h0[gg].x; Hid[col + 1][r0] = h0[gg].y;
        Hid[col + 2][r0] = h0[gg].z; Hid[col + 3][r0] = h0[gg].w;
        Hid[col + 0][r0 + 1] = h1[gg].x; Hid[col + 1][r0 + 1] = h1[gg].y;
        Hid[col + 2][r0 + 1] = h1[gg].z; Hid[col + 3][r0 + 1] = h1[gg].w;
    }
    __syncthreads();

    // ---- fc2 + residual(x2 from registers) ----
    float4 ob = *(const float4*)&fc2_b[c];
    float4 o0 = ob, o1 = ob;
    #pragma unroll 8
    for (int k = 0; k < 256; k++) {
        float2 a = *(const float2*)&Hid[k][r0];
        float4 w = *(const float4*)&fc2_w[k * 64 + c];
        o0.x += a.x * w.x; o0.y += a.x * w.y; o0.z += a.x * w.z; o0.w += a.x * w.w;
        o1.x += a.y * w.x; o1.y += a.y * w.y; o1.z += a.y * w.z; o1.w += a.y * w.w;
    }
    o0.x += a0.x; o0.y += a0.y; o0.z += a0.z; o0.w += a0.w;
    o1.x += a1.x; o1.y += a1.y; o1.z += a1.z; o1.w += a1.w;
    *(float4*)&out[(t0 + r0) * 64 + c] = o0;
    *(float4*)&out[(t0 + r0 + 1) * 64 + c] = o1;
}

extern "C" void kernel_launch(void* const* d_in, const int* in_sizes, int n_in,
                              void* d_out, int out_size, void* d_ws, size_t ws_size,
                              hipStream_t stream) {
    const float* x       = (const float*)d_in[0];
    const float* norm1_g = (const float*)d_in[1];
    const float* norm1_b = (const float*)d_in[2];
    const float* qkv_w   = (const float*)d_in[3];
    const float* qkv_b   = (const float*)d_in[4];
    const float* rpb     = (const float*)d_in[5];
    const float* proj_w  = (const float*)d_in[6];
    const float* proj_b  = (const float*)d_in[7];
    const float* norm2_g = (const float*)d_in[8];
    const float* norm2_b = (const float*)d_in[9];
    const float* fc1_w   = (const float*)d_in[10];
    const float* fc1_b   = (const float*)d_in[11];
    const float* fc2_w   = (const float*)d_in[12];
    const float* fc2_b   = (const float*)d_in[13];
    float* out = (float*)d_out;

    float* ws = (float*)d_ws;
    float* qkv      = ws;                      // 9216*192
    float* attn_out = qkv + NTOK * 192;        // 9216*64

    dim3 blk(256);
    // 1. qkv = LN1(x) @ qkv_w + qkv_b   (q pre-scaled)
    ln_gemm_kernel<<<dim3(NTOK / 32, 3), blk, 0, stream>>>(x, norm1_g, norm1_b, qkv_w, qkv_b, qkv);
    // 2. neighborhood attention (4 tokens/wave, shared k/v loads, DPP-only)
    na_attn_kernel<<<NTOK / 16, blk, 0, stream>>>(qkv, rpb, attn_out);
    // 3. out = fused proj+resid -> LN2 -> fc1+gelu -> fc2+resid
    mlp_fused_kernel<<<NTOK / 32, blk, 0, stream>>>(attn_out, x, proj_w, proj_b,
                                                    norm2_g, norm2_b, fc1_w, fc1_b,
                                                    fc2_w, fc2_b, out);
}

// Round 7
// 173.280 us; speedup vs baseline: 1.1844x; 1.1844x over previous
//
#include <hip/hip_runtime.h>
#include <math.h>

#define HH 96
#define WW 96
#define CC 64
#define NH 4
#define HD 16
#define KS 13
#define KK (KS*KS)
#define NTOK (HH*WW)

// ---------------- DPP cross-lane add (pure VALU, no LDS pipe) ---------------
// ctrl 0xB1 = quad_perm(1,0,3,2)  -> xor1 within quad
// ctrl 0x4E = quad_perm(2,3,0,1)  -> xor2 within quad
// ctrl 0x124 = row_ror:4, 0x128 = row_ror:8 (full-group sums: direction moot)
// ctrl 0x141 = row_half_mirror (valid only when quads already uniform)
template<int CTRL>
__device__ __forceinline__ float dpp_add(float p) {
    int t = __builtin_amdgcn_update_dpp(0, __float_as_int(p), CTRL, 0xF, 0xF, true);
    return p + __int_as_float(t);
}

__device__ __forceinline__ float dpp_reduce8(float p) {
    p = dpp_add<0xB1>(p);
    p = dpp_add<0x4E>(p);
    p = dpp_add<0x141>(p);
    return p;
}

// In-place LayerNorm of a 32-token tile stored TRANSPOSED in LDS: buf[ch][tok],
// ch = 0..63, tok = 0..31. 256 threads: 8 lanes per row, 8 channels per lane.
__device__ __forceinline__ void ln_rows32(float (*buf)[34],
                                          const float* __restrict__ g,
                                          const float* __restrict__ b,
                                          int tid) {
    int r  = tid >> 3;
    int c0 = (tid & 7) * 8;
    float v[8];
    float s = 0.0f;
    #pragma unroll
    for (int j = 0; j < 8; j++) { v[j] = buf[c0 + j][r]; s += v[j]; }
    s = dpp_reduce8(s);
    float mu = s * (1.0f / 64.0f);
    float s2 = 0.0f;
    #pragma unroll
    for (int j = 0; j < 8; j++) { float d = v[j] - mu; s2 += d * d; }
    s2 = dpp_reduce8(s2);
    float inv = rsqrtf(s2 * (1.0f / 64.0f) + 1e-5f);
    #pragma unroll
    for (int j = 0; j < 8; j++)
        buf[c0 + j][r] = (v[j] - mu) * inv * g[c0 + j] + b[c0 + j];
}

// ---------------- Fused LN1 + qkv GEMM --------------------------------------
__global__ __launch_bounds__(256) void ln_gemm_kernel(const float* __restrict__ x,
                                                      const float* __restrict__ g,
                                                      const float* __restrict__ b,
                                                      const float* __restrict__ W,
                                                      const float* __restrict__ bias,
                                                      float* __restrict__ out) {
    __shared__ float Ast[64][34];
    const int t0 = blockIdx.x * 32;
    const int tid = threadIdx.x;

    for (int i = tid; i < 32 * 64; i += 256) {
        int r = i >> 6, cc = i & 63;
        Ast[cc][r] = x[t0 * 64 + i];
    }
    __syncthreads();
    ln_rows32(Ast, g, b, tid);
    __syncthreads();

    const int tc = tid & 15;
    const int tr = tid >> 4;
    const int r0 = tr * 2;
    const int c  = blockIdx.y * 64 + tc * 4;

    float4 b4 = *(const float4*)&bias[c];
    float4 acc0 = b4, acc1 = b4;
    #pragma unroll 8
    for (int k = 0; k < 64; k++) {
        float2 a = *(const float2*)&Ast[k][r0];
        float4 w = *(const float4*)&W[k * 192 + c];
        acc0.x += a.x * w.x; acc0.y += a.x * w.y; acc0.z += a.x * w.z; acc0.w += a.x * w.w;
        acc1.x += a.y * w.x; acc1.y += a.y * w.y; acc1.z += a.y * w.z; acc1.w += a.y * w.w;
    }
    if (blockIdx.y == 0) {  // q section scaled by hd^-0.5 = 0.25
        acc0.x *= 0.25f; acc0.y *= 0.25f; acc0.z *= 0.25f; acc0.w *= 0.25f;
        acc1.x *= 0.25f; acc1.y *= 0.25f; acc1.z *= 0.25f; acc1.w *= 0.25f;
    }
    *(float4*)&out[(t0 + r0) * 192 + c] = acc0;
    *(float4*)&out[(t0 + r0 + 1) * 192 + c] = acc1;
}

// ---------------- Neighborhood attention: one wave per token ----------------
// qkv per token: [q(0..63) | k(64..127) | v(128..191)], head-major (n*16+d).
// Logits are small (|p+bias| < ~2), so softmax without max-shift is exact.
//
// Lane layout: head = lane>>4, slot = (lane>>2)&3, l = lane&3.
// Each lane holds dims 4l..4l+3 (float4) of its head; the 4 slots process 4
// different kw neighbors per iteration (kw = 4*i + slot). Dot product = 4
// in-lane FMAs + 2 quad_perm DPP adds. kw=12 tail: slot==0 only (quad-uniform).
// Epilogue: slot partials combined with row_ror:8 + row_ror:4.
//
// XCD-aware block swizzle (T1): grid 2304 = 8 XCDs x 288. Round-robin HW
// placement (bid%8 -> XCD) + swz = (bid&7)*288 + bid>>3 gives each XCD a
// contiguous 1152-token chunk (12 rows); its k/v window (~24 rows, ~1.2 MB)
// fits the 4 MiB XCD L2, so the 92%-overlapping neighbor windows of adjacent
// blocks become L2 hits instead of 8x-duplicated HBM fetches.
__global__ __launch_bounds__(256) void na_attn_kernel(const float* __restrict__ qkv,
                                                      const float* __restrict__ rpb,
                                                      float* __restrict__ out) {
    int wave = threadIdx.x >> 6;
    int lane = threadIdx.x & 63;
    int bid  = blockIdx.x;
    int swz  = (bid & 7) * 288 + (bid >> 3);   // bijective: 2304 % 8 == 0
    int token = swz * 4 + wave;
    int head = lane >> 4;
    int slot = (lane >> 2) & 3;
    int l    = lane & 3;
    int co   = head * HD + l * 4;

    int y = token / WW, x = token - y * WW;
    int gh = y % 3, ih = y / 3;
    int gw = x % 3, iw = x / 3;
    int sh = ih - 6; sh = sh < 0 ? 0 : (sh > 19 ? 19 : sh);
    int sw = iw - 6; sw = sw < 0 ? 0 : (sw > 19 ? 19 : sw);

    float4 q4 = *(const float4*)&qkv[token * 192 + co];
    const float* bias_h = rpb + head * 625 + (sw - iw + 12);

    // x-part of the neighbor address (floats), incl. this lane's slot offset:
    const int xpart = (gw + 3 * sw) * 192 + 64 + co + slot * 576;

    float4 acc = make_float4(0.f, 0.f, 0.f, 0.f);
    float s = 0.0f;

    for (int kh = 0; kh < KS; kh++) {
        int ny = gh + 3 * (sh + kh);
        const float* kp = qkv + ny * (WW * 192) + xpart;
        const float* bp = bias_h + (sh + kh - ih + 12) * 25;
        #pragma unroll
        for (int i = 0; i < 3; i++) {          // kw = 4*i + slot : 0..11
            float4 k4 = *(const float4*)(kp + i * 2304);
            float4 v4 = *(const float4*)(kp + i * 2304 + 64);
            float p = q4.x * k4.x + q4.y * k4.y + q4.z * k4.z + q4.w * k4.w;
            p = dpp_add<0xB1>(p);
            p = dpp_add<0x4E>(p);              // p = 16-dim dot (quad sum)
            float e = __expf(p + bp[4 * i + slot]);
            s += e;
            acc.x += e * v4.x; acc.y += e * v4.y; acc.z += e * v4.z; acc.w += e * v4.w;
        }
        if (slot == 0) {                        // tail kw = 12 (quad-uniform branch)
            float4 k4 = *(const float4*)(kp + 3 * 2304);
            float4 v4 = *(const float4*)(kp + 3 * 2304 + 64);
            float p = q4.x * k4.x + q4.y * k4.y + q4.z * k4.z + q4.w * k4.w;
            p = dpp_add<0xB1>(p);
            p = dpp_add<0x4E>(p);
            float e = __expf(p + bp[12]);
            s += e;
            acc.x += e * v4.x; acc.y += e * v4.y; acc.z += e * v4.z; acc.w += e * v4.w;
        }
    }

    // combine the 4 slot partials (lane bits 2..3): i, i+4, i+8, i+12 mod 16
    s = dpp_add<0x128>(s);  s = dpp_add<0x124>(s);
    acc.x = dpp_add<0x128>(acc.x); acc.x = dpp_add<0x124>(acc.x);
    acc.y = dpp_add<0x128>(acc.y); acc.y = dpp_add<0x124>(acc.y);
    acc.z = dpp_add<0x128>(acc.z); acc.z = dpp_add<0x124>(acc.z);
    acc.w = dpp_add<0x128>(acc.w); acc.w = dpp_add<0x124>(acc.w);

    if (slot == 0) {
        float inv = 1.0f / s;
        *(float4*)&out[token * CC + co] =
            make_float4(acc.x * inv, acc.y * inv, acc.z * inv, acc.w * inv);
    }
}

// ---------------- Fused proj+resid -> LN2 -> fc1+gelu -> fc2+resid ----------
__global__ __launch_bounds__(256) void mlp_fused_kernel(const float* __restrict__ attn_out,
                                                        const float* __restrict__ x,
                                                        const float* __restrict__ proj_w,
                                                        const float* __restrict__ proj_b,
                                                        const float* __restrict__ n2g,
                                                        const float* __restrict__ n2b,
                                                        const float* __restrict__ fc1_w,
                                                        const float* __restrict__ fc1_b,
                                                        const float* __restrict__ fc2_w,
                                                        const float* __restrict__ fc2_b,
                                                        float* __restrict__ out) {
    __shared__ float Ast[64][34];    // attn_out^T tile
    __shared__ float X2T[64][34];    // x2^T, then h2^T after LN
    __shared__ float Hid[256][34];   // hidden^T (gelu(fc1)) for fc2

    const int t0 = blockIdx.x * 32;
    const int tid = threadIdx.x;

    for (int i = tid; i < 32 * 64; i += 256) {
        int r = i >> 6, cc = i & 63;
        Ast[cc][r] = attn_out[t0 * 64 + i];
    }
    __syncthreads();

    const int tc = tid & 15;
    const int tr = tid >> 4;
    const int r0 = tr * 2;
    const int c  = tc * 4;

    // ---- proj + residual(x): x2 kept in registers (a0,a1) ----
    float4 pb = *(const float4*)&proj_b[c];
    float4 a0 = pb, a1 = pb;
    #pragma unroll 8
    for (int k = 0; k < 64; k++) {
        float2 a = *(const float2*)&Ast[k][r0];
        float4 w = *(const float4*)&proj_w[k * 64 + c];
        a0.x += a.x * w.x; a0.y += a.x * w.y; a0.z += a.x * w.z; a0.w += a.x * w.w;
        a1.x += a.y * w.x; a1.y += a.y * w.y; a1.z += a.y * w.z; a1.w += a.y * w.w;
    }
    {
        float4 x0 = *(const float4*)&x[(t0 + r0) * 64 + c];
        float4 x1 = *(const float4*)&x[(t0 + r0 + 1) * 64 + c];
        a0.x += x0.x; a0.y += x0.y; a0.z += x0.z; a0.w += x0.w;
        a1.x += x1.x; a1.y += x1.y; a1.z += x1.z; a1.w += x1.w;
    }
    X2T[c + 0][r0] = a0.x; X2T[c + 1][r0] = a0.y; X2T[c + 2][r0] = a0.z; X2T[c + 3][r0] = a0.w;
    X2T[c + 0][r0 + 1] = a1.x; X2T[c + 1][r0 + 1] = a1.y; X2T[c + 2][r0 + 1] = a1.z; X2T[c + 3][r0 + 1] = a1.w;
    __syncthreads();

    // ---- LN2 in place on X2T (raw x2 stays in a0/a1 for the final resid) ----
    ln_rows32(X2T, n2g, n2b, tid);
    __syncthreads();

    // ---- fc1 + gelu -> Hid (hidden^T). Each thread: 2 rows x 16 cols. ----
    float4 h0[4], h1[4];
    #pragma unroll
    for (int gg = 0; gg < 4; gg++) {
        float4 bb = *(const float4*)&fc1_b[c + gg * 64];
        h0[gg] = bb; h1[gg] = bb;
    }
    #pragma unroll 4
    for (int k = 0; k < 64; k++) {
        float2 a = *(const float2*)&X2T[k][r0];
        #pragma unroll
        for (int gg = 0; gg < 4; gg++) {
            float4 w = *(const float4*)&fc1_w[k * 256 + c + gg * 64];
            h0[gg].x += a.x * w.x; h0[gg].y += a.x * w.y; h0[gg].z += a.x * w.z; h0[gg].w += a.x * w.w;
            h1[gg].x += a.y * w.x; h1[gg].y += a.y * w.y; h1[gg].z += a.y * w.z; h1[gg].w += a.y * w.w;
        }
    }
    #define GELU1(v) v = 0.5f * v * (1.0f + erff(v * 0.70710678118f))
    #pragma unroll
    for (int gg = 0; gg < 4; gg++) {
        GELU1(h0[gg].x); GELU1(h0[gg].y); GELU1(h0[gg].z); GELU1(h0[gg].w);
        GELU1(h1[gg].x); GELU1(h1[gg].y); GELU1(h1[gg].z); GELU1(h1[gg].w);
    }
    #undef GELU1
    #pragma unroll
    for (int gg = 0; gg < 4; gg++) {
        int col = c + gg * 64;
        Hid[col + 0][r0] = h0[gg].x; Hid[col + 1][r0] = h0[gg].y;
        Hid[col + 2][r0] = h0[gg].z; Hid[col + 3][r0] = h0[gg].w;
        Hid[col + 0][r0 + 1] = h1[gg].x; Hid[col + 1][r0 + 1] = h1[gg].y;
        Hid[col + 2][r0 + 1] = h1[gg].z; Hid[col + 3][r0 + 1] = h1[gg].w;
    }
    __syncthreads();

    // ---- fc2 + residual(x2 from registers) ----
    float4 ob = *(const float4*)&fc2_b[c];
    float4 o0 = ob, o1 = ob;
    #pragma unroll 8
    for (int k = 0; k < 256; k++) {
        float2 a = *(const float2*)&Hid[k][r0];
        float4 w = *(const float4*)&fc2_w[k * 64 + c];
        o0.x += a.x * w.x; o0.y += a.x * w.y; o0.z += a.x * w.z; o0.w += a.x * w.w;
        o1.x += a.y * w.x; o1.y += a.y * w.y; o1.z += a.y * w.z; o1.w += a.y * w.w;
    }
    o0.x += a0.x; o0.y += a0.y; o0.z += a0.z; o0.w += a0.w;
    o1.x += a1.x; o1.y += a1.y; o1.z += a1.z; o1.w += a1.w;
    *(float4*)&out[(t0 + r0) * 64 + c] = o0;
    *(float4*)&out[(t0 + r0 + 1) * 64 + c] = o1;
}

extern "C" void kernel_launch(void* const* d_in, const int* in_sizes, int n_in,
                              void* d_out, int out_size, void* d_ws, size_t ws_size,
                              hipStream_t stream) {
    const float* x       = (const float*)d_in[0];
    const float* norm1_g = (const float*)d_in[1];
    const float* norm1_b = (const float*)d_in[2];
    const float* qkv_w   = (const float*)d_in[3];
    const float* qkv_b   = (const float*)d_in[4];
    const float* rpb     = (const float*)d_in[5];
    const float* proj_w  = (const float*)d_in[6];
    const float* proj_b  = (const float*)d_in[7];
    const float* norm2_g = (const float*)d_in[8];
    const float* norm2_b = (const float*)d_in[9];
    const float* fc1_w   = (const float*)d_in[10];
    const float* fc1_b   = (const float*)d_in[11];
    const float* fc2_w   = (const float*)d_in[12];
    const float* fc2_b   = (const float*)d_in[13];
    float* out = (float*)d_out;

    float* ws = (float*)d_ws;
    float* qkv      = ws;                      // 9216*192
    float* attn_out = qkv + NTOK * 192;        // 9216*64

    dim3 blk(256);
    // 1. qkv = LN1(x) @ qkv_w + qkv_b   (q pre-scaled)
    ln_gemm_kernel<<<dim3(NTOK / 32, 3), blk, 0, stream>>>(x, norm1_g, norm1_b, qkv_w, qkv_b, qkv);
    // 2. neighborhood attention (1 token/wave, 4 neighbors/iter, XCD swizzle)
    na_attn_kernel<<<NTOK / 4, blk, 0, stream>>>(qkv, rpb, attn_out);
    // 3. out = fused proj+resid -> LN2 -> fc1+gelu -> fc2+resid
    mlp_fused_kernel<<<NTOK / 32, blk, 0, stream>>>(attn_out, x, proj_w, proj_b,
                                                    norm2_g, norm2_b, fc1_w, fc1_b,
                                                    fc2_w, fc2_b, out);
}

// Round 8
// 170.950 us; speedup vs baseline: 1.2005x; 1.0136x over previous
//
#include <hip/hip_runtime.h>
#include <math.h>

#define HH 96
#define WW 96
#define CC 64
#define NH 4
#define HD 16
#define KS 13
#define KK (KS*KS)
#define NTOK (HH*WW)

// ---------------- DPP cross-lane add (pure VALU, no LDS pipe) ---------------
// ctrl 0xB1 = quad_perm(1,0,3,2)  -> xor1 within quad
// ctrl 0x4E = quad_perm(2,3,0,1)  -> xor2 within quad
// ctrl 0x124 = row_ror:4, 0x128 = row_ror:8 (full-group sums: direction moot)
// ctrl 0x141 = row_half_mirror (valid only when quads already uniform)
template<int CTRL>
__device__ __forceinline__ float dpp_add(float p) {
    int t = __builtin_amdgcn_update_dpp(0, __float_as_int(p), CTRL, 0xF, 0xF, true);
    return p + __int_as_float(t);
}

__device__ __forceinline__ float dpp_reduce8(float p) {
    p = dpp_add<0xB1>(p);
    p = dpp_add<0x4E>(p);
    p = dpp_add<0x141>(p);
    return p;
}

// In-place LayerNorm of a 32-token tile stored TRANSPOSED in LDS: buf[ch][tok],
// ch = 0..63, tok = 0..31. 256 threads: 8 lanes per row, 8 channels per lane.
__device__ __forceinline__ void ln_rows32(float (*buf)[34],
                                          const float* __restrict__ g,
                                          const float* __restrict__ b,
                                          int tid) {
    int r  = tid >> 3;
    int c0 = (tid & 7) * 8;
    float v[8];
    float s = 0.0f;
    #pragma unroll
    for (int j = 0; j < 8; j++) { v[j] = buf[c0 + j][r]; s += v[j]; }
    s = dpp_reduce8(s);
    float mu = s * (1.0f / 64.0f);
    float s2 = 0.0f;
    #pragma unroll
    for (int j = 0; j < 8; j++) { float d = v[j] - mu; s2 += d * d; }
    s2 = dpp_reduce8(s2);
    float inv = rsqrtf(s2 * (1.0f / 64.0f) + 1e-5f);
    #pragma unroll
    for (int j = 0; j < 8; j++)
        buf[c0 + j][r] = (v[j] - mu) * inv * g[c0 + j] + b[c0 + j];
}

// ---------------- Fused LN1 + qkv GEMM --------------------------------------
__global__ __launch_bounds__(256) void ln_gemm_kernel(const float* __restrict__ x,
                                                      const float* __restrict__ g,
                                                      const float* __restrict__ b,
                                                      const float* __restrict__ W,
                                                      const float* __restrict__ bias,
                                                      float* __restrict__ out) {
    __shared__ float Ast[64][34];
    const int t0 = blockIdx.x * 32;
    const int tid = threadIdx.x;

    for (int i = tid; i < 32 * 64; i += 256) {
        int r = i >> 6, cc = i & 63;
        Ast[cc][r] = x[t0 * 64 + i];
    }
    __syncthreads();
    ln_rows32(Ast, g, b, tid);
    __syncthreads();

    const int tc = tid & 15;
    const int tr = tid >> 4;
    const int r0 = tr * 2;
    const int c  = blockIdx.y * 64 + tc * 4;

    float4 b4 = *(const float4*)&bias[c];
    float4 acc0 = b4, acc1 = b4;
    #pragma unroll 8
    for (int k = 0; k < 64; k++) {
        float2 a = *(const float2*)&Ast[k][r0];
        float4 w = *(const float4*)&W[k * 192 + c];
        acc0.x += a.x * w.x; acc0.y += a.x * w.y; acc0.z += a.x * w.z; acc0.w += a.x * w.w;
        acc1.x += a.y * w.x; acc1.y += a.y * w.y; acc1.z += a.y * w.z; acc1.w += a.y * w.w;
    }
    if (blockIdx.y == 0) {  // q section scaled by hd^-0.5 = 0.25
        acc0.x *= 0.25f; acc0.y *= 0.25f; acc0.z *= 0.25f; acc0.w *= 0.25f;
        acc1.x *= 0.25f; acc1.y *= 0.25f; acc1.z *= 0.25f; acc1.w *= 0.25f;
    }
    *(float4*)&out[(t0 + r0) * 192 + c] = acc0;
    *(float4*)&out[(t0 + r0 + 1) * 192 + c] = acc1;
}

// ---------------- Neighborhood attention: one wave per token ----------------
// qkv per token: [q(0..63) | k(64..127) | v(128..191)], head-major (n*16+d).
// Logits are small (|p+bias| < ~2), so softmax without max-shift is exact.
//
// Wave structure (proven in R5/R7): head = lane>>4, slot = (lane>>2)&3,
// l = lane&3. Each lane holds dims 4l..4l+3 (float4); the 4 slots process 4
// different kw neighbors per iteration. Dot = 4 FMA + 2 quad_perm DPP adds.
// kw=12 tail: slot==0 only. Epilogue: row_ror:8 + row_ror:4.
//
// BLOCK COMPOSITION (new): the 4 waves of a block take tokens (y, g,
// iw0..iw0+3) — same dilation group, same row, consecutive group-cols. Their
// k/v windows share all rows and overlap 12/13 cols, so ~3/4 of each wave's
// k4/v4 loads hit L1 lines fetched by a sibling wave. (Consecutive tokens in
// raster order are in DIFFERENT dilation groups -> disjoint neighbor sets --
// that composition had zero intra-block reuse.) Occupancy unchanged: still
// one token per wave, 9216 waves.
// XCD swizzle: 2304 blocks = 8 x 288; each XCD gets 12 contiguous y-rows.
__global__ __launch_bounds__(256) void na_attn_kernel(const float* __restrict__ qkv,
                                                      const float* __restrict__ rpb,
                                                      float* __restrict__ out) {
    int wave = threadIdx.x >> 6;
    int lane = threadIdx.x & 63;
    int bid  = blockIdx.x;
    int swz  = (bid & 7) * 288 + (bid >> 3);   // bijective: 2304 % 8 == 0
    int y    = swz / 24;                       // spatial row
    int rem  = swz - y * 24;
    int gw   = rem >> 3;                       // dilation group (x % 3)
    int iw   = (rem & 7) * 4 + wave;           // group-col of this wave's token
    int token = y * WW + gw + 3 * iw;

    int head = lane >> 4;
    int slot = (lane >> 2) & 3;
    int l    = lane & 3;
    int co   = head * HD + l * 4;

    int gh = y % 3, ih = y / 3;
    int sh = ih - 6; sh = sh < 0 ? 0 : (sh > 19 ? 19 : sh);
    int sw = iw - 6; sw = sw < 0 ? 0 : (sw > 19 ? 19 : sw);

    float4 q4 = *(const float4*)&qkv[token * 192 + co];
    const float* bias_h = rpb + head * 625 + (sw - iw + 12);

    // x-part of the neighbor address (floats), incl. this lane's slot offset:
    const int xpart = (gw + 3 * sw) * 192 + 64 + co + slot * 576;

    float4 acc = make_float4(0.f, 0.f, 0.f, 0.f);
    float s = 0.0f;

    for (int kh = 0; kh < KS; kh++) {
        int ny = gh + 3 * (sh + kh);
        const float* kp = qkv + ny * (WW * 192) + xpart;
        const float* bp = bias_h + (sh + kh - ih + 12) * 25;
        #pragma unroll
        for (int i = 0; i < 3; i++) {          // kw = 4*i + slot : 0..11
            float4 k4 = *(const float4*)(kp + i * 2304);
            float4 v4 = *(const float4*)(kp + i * 2304 + 64);
            float p = q4.x * k4.x + q4.y * k4.y + q4.z * k4.z + q4.w * k4.w;
            p = dpp_add<0xB1>(p);
            p = dpp_add<0x4E>(p);              // p = 16-dim dot (quad sum)
            float e = __expf(p + bp[4 * i + slot]);
            s += e;
            acc.x += e * v4.x; acc.y += e * v4.y; acc.z += e * v4.z; acc.w += e * v4.w;
        }
        if (slot == 0) {                        // tail kw = 12 (quad-uniform branch)
            float4 k4 = *(const float4*)(kp + 3 * 2304);
            float4 v4 = *(const float4*)(kp + 3 * 2304 + 64);
            float p = q4.x * k4.x + q4.y * k4.y + q4.z * k4.z + q4.w * k4.w;
            p = dpp_add<0xB1>(p);
            p = dpp_add<0x4E>(p);
            float e = __expf(p + bp[12]);
            s += e;
            acc.x += e * v4.x; acc.y += e * v4.y; acc.z += e * v4.z; acc.w += e * v4.w;
        }
    }

    // combine the 4 slot partials (lane bits 2..3): i, i+4, i+8, i+12 mod 16
    s = dpp_add<0x128>(s);  s = dpp_add<0x124>(s);
    acc.x = dpp_add<0x128>(acc.x); acc.x = dpp_add<0x124>(acc.x);
    acc.y = dpp_add<0x128>(acc.y); acc.y = dpp_add<0x124>(acc.y);
    acc.z = dpp_add<0x128>(acc.z); acc.z = dpp_add<0x124>(acc.z);
    acc.w = dpp_add<0x128>(acc.w); acc.w = dpp_add<0x124>(acc.w);

    if (slot == 0) {
        float inv = 1.0f / s;
        *(float4*)&out[token * CC + co] =
            make_float4(acc.x * inv, acc.y * inv, acc.z * inv, acc.w * inv);
    }
}

// ---------------- Fused proj+resid -> LN2 -> fc1+gelu -> fc2+resid ----------
__global__ __launch_bounds__(256) void mlp_fused_kernel(const float* __restrict__ attn_out,
                                                        const float* __restrict__ x,
                                                        const float* __restrict__ proj_w,
                                                        const float* __restrict__ proj_b,
                                                        const float* __restrict__ n2g,
                                                        const float* __restrict__ n2b,
                                                        const float* __restrict__ fc1_w,
                                                        const float* __restrict__ fc1_b,
                                                        const float* __restrict__ fc2_w,
                                                        const float* __restrict__ fc2_b,
                                                        float* __restrict__ out) {
    __shared__ float Ast[64][34];    // attn_out^T tile
    __shared__ float X2T[64][34];    // x2^T, then h2^T after LN
    __shared__ float Hid[256][34];   // hidden^T (gelu(fc1)) for fc2

    const int t0 = blockIdx.x * 32;
    const int tid = threadIdx.x;

    for (int i = tid; i < 32 * 64; i += 256) {
        int r = i >> 6, cc = i & 63;
        Ast[cc][r] = attn_out[t0 * 64 + i];
    }
    __syncthreads();

    const int tc = tid & 15;
    const int tr = tid >> 4;
    const int r0 = tr * 2;
    const int c  = tc * 4;

    // ---- proj + residual(x): x2 kept in registers (a0,a1) ----
    float4 pb = *(const float4*)&proj_b[c];
    float4 a0 = pb, a1 = pb;
    #pragma unroll 8
    for (int k = 0; k < 64; k++) {
        float2 a = *(const float2*)&Ast[k][r0];
        float4 w = *(const float4*)&proj_w[k * 64 + c];
        a0.x += a.x * w.x; a0.y += a.x * w.y; a0.z += a.x * w.z; a0.w += a.x * w.w;
        a1.x += a.y * w.x; a1.y += a.y * w.y; a1.z += a.y * w.z; a1.w += a.y * w.w;
    }
    {
        float4 x0 = *(const float4*)&x[(t0 + r0) * 64 + c];
        float4 x1 = *(const float4*)&x[(t0 + r0 + 1) * 64 + c];
        a0.x += x0.x; a0.y += x0.y; a0.z += x0.z; a0.w += x0.w;
        a1.x += x1.x; a1.y += x1.y; a1.z += x1.z; a1.w += x1.w;
    }
    X2T[c + 0][r0] = a0.x; X2T[c + 1][r0] = a0.y; X2T[c + 2][r0] = a0.z; X2T[c + 3][r0] = a0.w;
    X2T[c + 0][r0 + 1] = a1.x; X2T[c + 1][r0 + 1] = a1.y; X2T[c + 2][r0 + 1] = a1.z; X2T[c + 3][r0 + 1] = a1.w;
    __syncthreads();

    // ---- LN2 in place on X2T (raw x2 stays in a0/a1 for the final resid) ----
    ln_rows32(X2T, n2g, n2b, tid);
    __syncthreads();

    // ---- fc1 + gelu -> Hid (hidden^T). Each thread: 2 rows x 16 cols. ----
    float4 h0[4], h1[4];
    #pragma unroll
    for (int gg = 0; gg < 4; gg++) {
        float4 bb = *(const float4*)&fc1_b[c + gg * 64];
        h0[gg] = bb; h1[gg] = bb;
    }
    #pragma unroll 4
    for (int k = 0; k < 64; k++) {
        float2 a = *(const float2*)&X2T[k][r0];
        #pragma unroll
        for (int gg = 0; gg < 4; gg++) {
            float4 w = *(const float4*)&fc1_w[k * 256 + c + gg * 64];
            h0[gg].x += a.x * w.x; h0[gg].y += a.x * w.y; h0[gg].z += a.x * w.z; h0[gg].w += a.x * w.w;
            h1[gg].x += a.y * w.x; h1[gg].y += a.y * w.y; h1[gg].z += a.y * w.z; h1[gg].w += a.y * w.w;
        }
    }
    #define GELU1(v) v = 0.5f * v * (1.0f + erff(v * 0.70710678118f))
    #pragma unroll
    for (int gg = 0; gg < 4; gg++) {
        GELU1(h0[gg].x); GELU1(h0[gg].y); GELU1(h0[gg].z); GELU1(h0[gg].w);
        GELU1(h1[gg].x); GELU1(h1[gg].y); GELU1(h1[gg].z); GELU1(h1[gg].w);
    }
    #undef GELU1
    #pragma unroll
    for (int gg = 0; gg < 4; gg++) {
        int col = c + gg * 64;
        Hid[col + 0][r0] = h0[gg].x; Hid[col + 1][r0] = h0[gg].y;
        Hid[col + 2][r0] = h0[gg].z; Hid[col + 3][r0] = h0[gg].w;
        Hid[col + 0][r0 + 1] = h1[gg].x; Hid[col + 1][r0 + 1] = h1[gg].y;
        Hid[col + 2][r0 + 1] = h1[gg].z; Hid[col + 3][r0 + 1] = h1[gg].w;
    }
    __syncthreads();

    // ---- fc2 + residual(x2 from registers) ----
    float4 ob = *(const float4*)&fc2_b[c];
    float4 o0 = ob, o1 = ob;
    #pragma unroll 8
    for (int k = 0; k < 256; k++) {
        float2 a = *(const float2*)&Hid[k][r0];
        float4 w = *(const float4*)&fc2_w[k * 64 + c];
        o0.x += a.x * w.x; o0.y += a.x * w.y; o0.z += a.x * w.z; o0.w += a.x * w.w;
        o1.x += a.y * w.x; o1.y += a.y * w.y; o1.z += a.y * w.z; o1.w += a.y * w.w;
    }
    o0.x += a0.x; o0.y += a0.y; o0.z += a0.z; o0.w += a0.w;
    o1.x += a1.x; o1.y += a1.y; o1.z += a1.z; o1.w += a1.w;
    *(float4*)&out[(t0 + r0) * 64 + c] = o0;
    *(float4*)&out[(t0 + r0 + 1) * 64 + c] = o1;
}

extern "C" void kernel_launch(void* const* d_in, const int* in_sizes, int n_in,
                              void* d_out, int out_size, void* d_ws, size_t ws_size,
                              hipStream_t stream) {
    const float* x       = (const float*)d_in[0];
    const float* norm1_g = (const float*)d_in[1];
    const float* norm1_b = (const float*)d_in[2];
    const float* qkv_w   = (const float*)d_in[3];
    const float* qkv_b   = (const float*)d_in[4];
    const float* rpb     = (const float*)d_in[5];
    const float* proj_w  = (const float*)d_in[6];
    const float* proj_b  = (const float*)d_in[7];
    const float* norm2_g = (const float*)d_in[8];
    const float* norm2_b = (const float*)d_in[9];
    const float* fc1_w   = (const float*)d_in[10];
    const float* fc1_b   = (const float*)d_in[11];
    const float* fc2_w   = (const float*)d_in[12];
    const float* fc2_b   = (const float*)d_in[13];
    float* out = (float*)d_out;

    float* ws = (float*)d_ws;
    float* qkv      = ws;                      // 9216*192
    float* attn_out = qkv + NTOK * 192;        // 9216*64

    dim3 blk(256);
    // 1. qkv = LN1(x) @ qkv_w + qkv_b   (q pre-scaled)
    ln_gemm_kernel<<<dim3(NTOK / 32, 3), blk, 0, stream>>>(x, norm1_g, norm1_b, qkv_w, qkv_b, qkv);
    // 2. neighborhood attention (1 token/wave; block = 4 window-sharing tokens)
    na_attn_kernel<<<NTOK / 4, blk, 0, stream>>>(qkv, rpb, attn_out);
    // 3. out = fused proj+resid -> LN2 -> fc1+gelu -> fc2+resid
    mlp_fused_kernel<<<NTOK / 32, blk, 0, stream>>>(attn_out, x, proj_w, proj_b,
                                                    norm2_g, norm2_b, fc1_w, fc1_b,
                                                    fc2_w, fc2_b, out);
}